// Round 8
// baseline (195.253 us; speedup 1.0000x reference)
//
#include <hip/hip_runtime.h>

typedef __bf16 bf16_t;
typedef __bf16 bf16x8 __attribute__((ext_vector_type(8)));
typedef __bf16 bf16x4 __attribute__((ext_vector_type(4)));
typedef _Float16 f16x4 __attribute__((ext_vector_type(4)));
typedef _Float16 f16x8 __attribute__((ext_vector_type(8)));
typedef float f32x4 __attribute__((ext_vector_type(4)));

// async global->LDS, 16B per lane. LDS dest must be wave-uniform base + lane*16.
__device__ __forceinline__ void gl_lds16(const void* g, void* l) {
  __builtin_amdgcn_global_load_lds(
      (const __attribute__((address_space(1))) unsigned int*)g,
      (__attribute__((address_space(3))) unsigned int*)l, 16, 0, 0);
}

// ---------------------------------------------------------------- fused prep kernel
// [0,2048): cast hs->bf16 ; [2048,4096): cast tk->bf16  (8 elems/thread, 16B stores)
// [4096,5632): transpose Wc ; [5632,6144): transpose Wp ; [6144,8192): tv^T -> fp16 (key-permuted)
// Transposes: 64x32 fp32 tile in LDS, 16B vector stores.
__global__ __launch_bounds__(256) void prep_kernel(
    const float* __restrict__ hs, const float* __restrict__ tk, const float* __restrict__ tv,
    const float* __restrict__ Wc, const float* __restrict__ Wp,
    bf16_t* __restrict__ Ahs, bf16_t* __restrict__ Ktb, _Float16* __restrict__ Vtb,
    bf16_t* __restrict__ WcT, bf16_t* __restrict__ WpT) {
  const int blk = blockIdx.x;
  const int tid = threadIdx.x;
  if (blk < 4096) {
    const float4* src = (blk < 2048) ? (const float4*)hs : (const float4*)tk;
    bf16x8* dst = (blk < 2048) ? (bf16x8*)Ahs : (bf16x8*)Ktb;
    int i = (blk & 2047) * 256 + tid;  // units of 8 floats
    float4 v0 = src[2 * i], v1 = src[2 * i + 1];
    bf16x8 o;
    o[0] = (bf16_t)v0.x; o[1] = (bf16_t)v0.y; o[2] = (bf16_t)v0.z; o[3] = (bf16_t)v0.w;
    o[4] = (bf16_t)v1.x; o[5] = (bf16_t)v1.y; o[6] = (bf16_t)v1.z; o[7] = (bf16_t)v1.w;
    dst[i] = o;
  } else {
    __shared__ float tile[32][65];  // [col][row], pad 65 -> 2-way max on write/read
    const float* in; bf16_t* out; int C, r0, c0; size_t base = 0; bool isV = false;
    if (blk < 5632) {
      int t = blk - 4096; in = Wc; out = WcT; C = 3072;
      r0 = (t / 96) * 64; c0 = (t % 96) * 32;
    } else if (blk < 6144) {
      int t = blk - 5632; in = Wp; out = WpT; C = 1024;
      r0 = (t >> 5) * 64; c0 = (t & 31) * 32;
    } else {
      int t = blk - 6144; int z = t >> 5, rest = t & 31;
      in = tv; out = nullptr; isV = true; C = 64; base = (size_t)z * 65536;
      r0 = (rest >> 1) * 64; c0 = (rest & 1) * 32;
    }
    // read 64 rows x 32 cols, write transposed into LDS
    {
      int rr = tid >> 2, cq = (tid & 3) << 3;
      const float* sp = in + base + (size_t)(r0 + rr) * C + c0 + cq;
      float4 v0 = *(const float4*)sp, v1 = *(const float4*)(sp + 4);
      tile[cq + 0][rr] = v0.x; tile[cq + 1][rr] = v0.y;
      tile[cq + 2][rr] = v0.z; tile[cq + 3][rr] = v0.w;
      tile[cq + 4][rr] = v1.x; tile[cq + 5][rr] = v1.y;
      tile[cq + 6][rr] = v1.z; tile[cq + 7][rr] = v1.w;
    }
    __syncthreads();
    int y = tid >> 3, l = tid & 7;
    if (isV) {
      // gather with key permutation m=b5,b3,b2,b4,b1,b0 (pairs PV chunk quads into 16B)
      f16x8 o;
#pragma unroll
      for (int j = 0; j < 8; j++) {
        int k = ((l & 4) << 3) | ((j & 4) << 2) | ((l & 2) << 2) | ((l & 1) << 2) | (j & 3);
        o[j] = (_Float16)tile[y][k];
      }
      *(f16x8*)(Vtb + base + (size_t)(c0 + y) * 1024 + r0 + (l << 3)) = o;
    } else {
      const float* rowp = &tile[y][l << 3];
      bf16x8 o;
#pragma unroll
      for (int j = 0; j < 8; j++) o[j] = (bf16_t)rowp[j];
      *(bf16x8*)(out + (size_t)(c0 + y) * 1024 + r0 + (l << 3)) = o;
    }
  }
}

// ---------------------------------------------------------------- QKV GEMM (standard form)
// Aqkv = Ahs(4096x1024) @ Wc(1024x3072) + bc, bf16 out. m97-proven 128x128 tile,
// 256 thr / 4 waves (2x2, 64x64 each), single-buffered 2-barrier loop, gl_lds16 staging,
// XOR-swizzled LDS, XCD-contiguous block swizzle. ~3 blocks/CU.
__global__ __launch_bounds__(256) void qkv_gemm_kernel(
    const bf16_t* __restrict__ Ahs, const bf16_t* __restrict__ WcT,
    const float* __restrict__ bc, bf16_t* __restrict__ Aqkv) {
  const int bid = blockIdx.x;                   // 768 = 32 m-tiles x 24 n-tiles
  const int swz = (bid & 7) * 96 + (bid >> 3);  // 8 XCDs x 96 contiguous tiles
  const int bm = swz / 24, bn = swz % 24;
  const int m0 = bm * 128, n0 = bn * 128;
  const int tid = threadIdx.x, wave = tid >> 6, lane = tid & 63;
  const int c = lane & 15, qd = lane >> 4;
  const int wr = wave >> 1, wc = wave & 1;

  __shared__ __align__(16) bf16_t Asm[8192];
  __shared__ __align__(16) bf16_t Bsm[8192];

  f32x4 acc[4][4];
#pragma unroll
  for (int i = 0; i < 4; i++)
#pragma unroll
    for (int j = 0; j < 4; j++) acc[i][j] = (f32x4){0.f, 0.f, 0.f, 0.f};

  for (int kt = 0; kt < 16; kt++) {
#pragma unroll
    for (int p = 0; p < 4; p++) {
      int chunk = p * 256 + tid;
      int row = chunk >> 3, sb = chunk & 7, kb = sb ^ (row & 7);
      gl_lds16(Ahs + (size_t)(m0 + row) * 1024 + kt * 64 + kb * 8, Asm + chunk * 8);
      gl_lds16(WcT + (size_t)(n0 + row) * 1024 + kt * 64 + kb * 8, Bsm + chunk * 8);
    }
    __syncthreads();
#pragma unroll
    for (int kk = 0; kk < 2; kk++) {
      bf16x8 af[4], bfr[4];
#pragma unroll
      for (int i = 0; i < 4; i++) {
        int arow = wr * 64 + 16 * i + c;
        af[i] = *(const bf16x8*)(&Asm[arow * 64 + (((4 * kk + qd) ^ (c & 7)) << 3)]);
        int brow = wc * 64 + 16 * i + c;
        bfr[i] = *(const bf16x8*)(&Bsm[brow * 64 + (((4 * kk + qd) ^ (c & 7)) << 3)]);
      }
#pragma unroll
      for (int i = 0; i < 4; i++)
#pragma unroll
        for (int j = 0; j < 4; j++)
          acc[i][j] = __builtin_amdgcn_mfma_f32_16x16x32_bf16(af[i], bfr[j], acc[i][j], 0, 0, 0);
    }
    __syncthreads();
  }
  // epilogue: bias + bf16 store
#pragma unroll
  for (int j = 0; j < 4; j++) {
    int n = n0 + wc * 64 + 16 * j + c;
    float bv = bc[n];
#pragma unroll
    for (int i = 0; i < 4; i++)
#pragma unroll
      for (int r = 0; r < 4; r++) {
        int m = m0 + wr * 64 + 16 * i + 4 * qd + r;
        Aqkv[(size_t)m * 3072 + n] = (bf16_t)(acc[i][j][r] + bv);
      }
  }
}

// ---------------------------------------------------------------- attention kernel
// Two-strip blocks (R3-proven): waves 0-3 own queries [64q,+64), waves 4-7 own [64(15-q),+64).
// Init: load q/k/v head-slices from Aqkv -> wself, O-init, q B-frags; then flash loop over
// textual K/V (identical to the verified fused phase 2).
#define ATTN_M 12.0f
__global__ __launch_bounds__(512, 4) void attn_kernel(
    const bf16_t* __restrict__ Aqkv,
    const bf16_t* __restrict__ Ktxt, const _Float16* __restrict__ VtxtT,
    bf16_t* __restrict__ Aout) {
  const int bh = blockIdx.x;  // 0..63 ; id%8 = bh&7 -> h-locality per XCD
  const int y = blockIdx.y;   // 0..7
  const int q = (y < 4) ? y : 11 - y;  // co-resident pair (y,y+4) -> (q, 7-q)
  const int qlo = q, qhi = 15 - q;     // this block's two query strips (64 rows each)
  const int b = bh >> 4, h = bh & 15;
  const int tid = threadIdx.x, wave = tid >> 6, lane = tid & 63;
  const int c = lane & 15, qd = lane >> 4;
  const int i_base = (wave < 4) ? qlo * 64 + wave * 16 : qhi * 64 + (wave & 3) * 16;
  const int kt_max = qhi;  // inclusive

  const bf16_t* Ktb = Ktxt + (size_t)bh * 65536;
  const _Float16* Vtb = VtxtT + (size_t)bh * 65536;

  __shared__ __align__(16) char pool[49152];
  bf16_t* Qsm = (bf16_t*)pool;                 // [0,16K)   q swizzled (persistent)
  bf16_t* Ksf = (bf16_t*)(pool + 16384);       // [16K,32K) k self (transient)
  bf16_t* Vsf = (bf16_t*)(pool + 32768);       // [32K,48K) v self (transient)
  bf16_t* KsmB = (bf16_t*)(pool + 16384);      // [16K,32K) text Ksm[2][4096]
  _Float16* VsmB = (_Float16*)(pool + 32768);  // [32K,48K) text Vsm[2][4096]

  // stage q/k/v self tiles (rows = two strips, cols = head h slice of each segment)
#pragma unroll
  for (int sgp = 0; sgp < 6; sgp++) {
    int seg = sgp >> 1, p = sgp & 1;
    int chunk = p * 512 + tid;
    int row = chunk >> 3, sb = chunk & 7, kb = sb ^ (row & 7);
    int grow = b * 1024 + ((row < 64) ? qlo * 64 + row : qhi * 64 + (row - 64));
    bf16_t* dst = (seg == 0) ? Qsm : (seg == 1) ? Ksf : Vsf;
    gl_lds16(Aqkv + (size_t)grow * 3072 + seg * 1024 + h * 64 + kb * 8, dst + chunk * 8);
  }
  __syncthreads();

  // self logits: dot(q,k) per query row (4 lanes per row, 16 d's each)
  float dotv;
  {
    const int i = wave * 16 + (lane >> 2);
    const int t = lane & 3;
    const int ib = i & 7;
    bf16x8 q0 = *(const bf16x8*)(&Qsm[i * 64 + (((2 * t) ^ ib) << 3)]);
    bf16x8 q1 = *(const bf16x8*)(&Qsm[i * 64 + (((2 * t + 1) ^ ib) << 3)]);
    bf16x8 k0 = *(const bf16x8*)(&Ksf[i * 64 + (((2 * t) ^ ib) << 3)]);
    bf16x8 k1 = *(const bf16x8*)(&Ksf[i * 64 + (((2 * t + 1) ^ ib) << 3)]);
    float s = 0.f;
#pragma unroll
    for (int e = 0; e < 8; e++) s += (float)q0[e] * (float)k0[e];
#pragma unroll
    for (int e = 0; e < 8; e++) s += (float)q1[e] * (float)k1[e];
    s += __shfl_xor(s, 1, 64);
    s += __shfl_xor(s, 2, 64);
    dotv = s;
  }
  float wself[4];
#pragma unroll
  for (int r = 0; r < 4; r++)
    wself[r] = __expf(__shfl(dotv, 16 * qd + 4 * r, 64) * 0.125f - ATTN_M);

  // O init from v self
  f32x4 O[4];
#pragma unroll
  for (int u = 0; u < 4; u++)
#pragma unroll
    for (int r = 0; r < 4; r++) {
      int row = wave * 16 + 4 * qd + r, col = 16 * u + c;
      int ch = (col >> 3) ^ (row & 7);
      O[u][r] = wself[r] * (float)Vsf[row * 64 + (ch << 3) + (col & 7)];
    }

  // q B-operand frags
  bf16x8 aq[2];
#pragma unroll
  for (int kk = 0; kk < 2; kk++) {
    int qrow = wave * 16 + c;
    aq[kk] = *(const bf16x8*)(&Qsm[qrow * 64 + (((4 * kk + qd) ^ (c & 7)) << 3)]);
  }
  __syncthreads();  // Ksf/Vsf reads done; text staging may overwrite [16K,48K)

  // stage text K/V tile 0 (async)
  {
    int row = tid >> 3, sb = tid & 7, kb = sb ^ (row & 7);
    gl_lds16(Ktb + (size_t)row * 64 + kb * 8, KsmB + tid * 8);
    gl_lds16(Vtb + (size_t)row * 1024 + kb * 8, VsmB + tid * 8);
  }

  // flash attention over textual K/V
  float l_loc = 0.f;
  for (int kt = 0; kt <= kt_max; kt++) {
    __syncthreads();
    if (kt < kt_max) {
      int nb = (kt + 1) & 1;
      int row = tid >> 3, sb = tid & 7, kb = sb ^ (row & 7);
      gl_lds16(Ktb + (size_t)((kt + 1) * 64 + row) * 64 + kb * 8, KsmB + nb * 4096 + tid * 8);
      gl_lds16(Vtb + (size_t)row * 1024 + (kt + 1) * 64 + kb * 8, VsmB + nb * 4096 + tid * 8);
    }
    if (64 * kt >= i_base + 16) continue;  // wave fully masked for this tile
    const bf16_t* Ks = KsmB + (kt & 1) * 4096;
    const _Float16* Vs = VsmB + (kt & 1) * 4096;

    // S^T[key][query]: A = K-tile, B = Q  ->  C-frag: key = 16t+4qd+r, query = c
    f32x4 sc[4];
#pragma unroll
    for (int t = 0; t < 4; t++) sc[t] = (f32x4){0.f, 0.f, 0.f, 0.f};
    __builtin_amdgcn_s_setprio(1);  // T5
#pragma unroll
    for (int kk = 0; kk < 2; kk++) {
#pragma unroll
      for (int t = 0; t < 4; t++) {
        int row = 16 * t + c;
        bf16x8 bk = *(const bf16x8*)(&Ks[row * 64 + (((4 * kk + qd) ^ (row & 7)) << 3)]);
        sc[t] = __builtin_amdgcn_mfma_f32_16x16x32_bf16(bk, aq[kk], sc[t], 0, 0, 0);
      }
    }
    __builtin_amdgcn_s_setprio(0);
    const bool edge = (64 * kt + 63 >= i_base);
    f16x4 pa[4];  // P^T frags == A-operand of 16x16x16 f16 (m=query=c, k=4qd+j)
    if (!edge) {
#pragma unroll
      for (int t = 0; t < 4; t++)
#pragma unroll
        for (int r = 0; r < 4; r++) {
          float p = __expf(sc[t][r] * 0.125f - ATTN_M);
          l_loc += p;
          pa[t][r] = (_Float16)p;
        }
    } else {
#pragma unroll
      for (int t = 0; t < 4; t++)
#pragma unroll
        for (int r = 0; r < 4; r++) {
          bool masked = (64 * kt + 16 * t + 4 * qd + r >= i_base + c);
          float p = masked ? 0.f : __expf(sc[t][r] * 0.125f - ATTN_M);
          l_loc += p;
          pa[t][r] = (_Float16)p;
        }
    }
    // PV: V stored key-permuted so chunk-pair (2tp,2tp+1) quads sit in one 16B block
    __builtin_amdgcn_s_setprio(1);
#pragma unroll
    for (int tp = 0; tp < 2; tp++) {
#pragma unroll
      for (int u = 0; u < 4; u++) {
        int row = 16 * u + c;
        f16x8 vv = *(const f16x8*)(&Vs[row * 64 + (((4 * tp + qd) ^ (row & 7)) << 3)]);
        f16x4 vlo = __builtin_shufflevector(vv, vv, 0, 1, 2, 3);
        f16x4 vhi = __builtin_shufflevector(vv, vv, 4, 5, 6, 7);
        O[u] = __builtin_amdgcn_mfma_f32_16x16x16f16(pa[2 * tp], vlo, O[u], 0, 0, 0);
        O[u] = __builtin_amdgcn_mfma_f32_16x16x16f16(pa[2 * tp + 1], vhi, O[u], 0, 0, 0);
      }
    }
    __builtin_amdgcn_s_setprio(0);
  }

  l_loc += __shfl_xor(l_loc, 16, 64);
  l_loc += __shfl_xor(l_loc, 32, 64);
#pragma unroll
  for (int r = 0; r < 4; r++) {
    float lq = __shfl(l_loc, 4 * qd + r, 16);
    float inv = 1.0f / (lq + wself[r]);
    int i = i_base + 4 * qd + r;
#pragma unroll
    for (int u = 0; u < 4; u++)
      Aout[((size_t)b * 1024 + i) * 1024 + h * 64 + 16 * u + c] = (bf16_t)(O[u][r] * inv);
  }
}

// ---------------------------------------------------------------- GEMM 2: out = Aout @ Wp + bp
// 64x128 tile -> 512 blocks (2/CU, 16 waves/CU) + explicit LDS double-buffer.
__global__ __launch_bounds__(256) void gemm_out_kernel(
    const bf16_t* __restrict__ A, const bf16_t* __restrict__ Bt, const float* __restrict__ bias,
    float* __restrict__ out) {
  __shared__ bf16_t Asm[2][4096];
  __shared__ bf16_t Bsm[2][8192];
  const int tid = threadIdx.x;
  const int wave = tid >> 6, lane = tid & 63;
  const int c = lane & 15, qd = lane >> 4;
  const int wn = wave * 32;
  const int m0 = blockIdx.y * 64, n0 = blockIdx.x * 128;

  f32x4 acc[4][2];
#pragma unroll
  for (int i = 0; i < 4; i++)
#pragma unroll
    for (int j = 0; j < 2; j++) acc[i][j] = (f32x4){0.f, 0.f, 0.f, 0.f};

#pragma unroll
  for (int p = 0; p < 2; p++) {
    int chunk = p * 256 + tid;
    int row = chunk >> 3, sb = chunk & 7, kb = sb ^ (row & 7);
    gl_lds16(A + (size_t)(m0 + row) * 1024 + kb * 8, &Asm[0][chunk * 8]);
  }
#pragma unroll
  for (int p = 0; p < 4; p++) {
    int chunk = p * 256 + tid;
    int row = chunk >> 3, sb = chunk & 7, kb = sb ^ (row & 7);
    gl_lds16(Bt + (size_t)(n0 + row) * 1024 + kb * 8, &Bsm[0][chunk * 8]);
  }
  for (int it = 0; it < 16; it++) {
    __syncthreads();
    if (it < 15) {
      int nbuf = (it + 1) & 1, kt = (it + 1) * 64;
#pragma unroll
      for (int p = 0; p < 2; p++) {
        int chunk = p * 256 + tid;
        int row = chunk >> 3, sb = chunk & 7, kb = sb ^ (row & 7);
        gl_lds16(A + (size_t)(m0 + row) * 1024 + kt + kb * 8, &Asm[nbuf][chunk * 8]);
      }
#pragma unroll
      for (int p = 0; p < 4; p++) {
        int chunk = p * 256 + tid;
        int row = chunk >> 3, sb = chunk & 7, kb = sb ^ (row & 7);
        gl_lds16(Bt + (size_t)(n0 + row) * 1024 + kt + kb * 8, &Bsm[nbuf][chunk * 8]);
      }
    }
    const int bs = it & 1;
#pragma unroll
    for (int kk = 0; kk < 2; kk++) {
      bf16x8 af[4], bfr[2];
#pragma unroll
      for (int i = 0; i < 4; i++) {
        int row = 16 * i + c;
        af[i] = *(const bf16x8*)(&Asm[bs][row * 64 + (((4 * kk + qd) ^ (row & 7)) << 3)]);
      }
#pragma unroll
      for (int j = 0; j < 2; j++) {
        int row = wn + 16 * j + c;
        bfr[j] = *(const bf16x8*)(&Bsm[bs][row * 64 + (((4 * kk + qd) ^ (row & 7)) << 3)]);
      }
#pragma unroll
      for (int i = 0; i < 4; i++)
#pragma unroll
        for (int j = 0; j < 2; j++)
          acc[i][j] = __builtin_amdgcn_mfma_f32_16x16x32_bf16(af[i], bfr[j], acc[i][j], 0, 0, 0);
    }
  }
#pragma unroll
  for (int j = 0; j < 2; j++) {
    int n = n0 + wn + 16 * j + c;
    float bv = bias[n];
#pragma unroll
    for (int i = 0; i < 4; i++) {
#pragma unroll
      for (int r = 0; r < 4; r++) {
        int m = m0 + 16 * i + 4 * qd + r;
        out[(size_t)m * 1024 + n] = acc[i][j][r] + bv;
      }
    }
  }
}

// ----------------------------------------------------------------
extern "C" void kernel_launch(void* const* d_in, const int* in_sizes, int n_in,
                              void* d_out, int out_size, void* d_ws, size_t ws_size,
                              hipStream_t stream) {
  const float* hs = (const float*)d_in[0];
  const float* tk = (const float*)d_in[1];
  const float* tv = (const float*)d_in[2];
  const float* Wc = (const float*)d_in[3];
  const float* bc = (const float*)d_in[4];
  const float* Wp = (const float*)d_in[5];
  const float* bp = (const float*)d_in[6];
  float* out = (float*)d_out;

  bf16_t* ws = (bf16_t*)d_ws;
  const size_t M1 = 1u << 20;
  bf16_t* Ahs  = ws;                          // hs bf16 (4096 x 1024)          [0,4M)
  bf16_t* WcT  = ws + 4 * M1;                 // Wc^T (3072 x 1024)             [4M,7M)
  bf16_t* WpT  = ws + 7 * M1;                 // Wp^T (1024 x 1024)             [7M,8M)
  bf16_t* Ktb  = ws + 8 * M1;                 // textual_key bf16 (B,H,S,HD)    [8M,12M)
  _Float16* Vtb = (_Float16*)(ws + 12 * M1);  // textual_value^T fp16, permuted [12M,16M)
  bf16_t* Aqkv = ws + 16 * M1;                // qkv GEMM out (4096 x 3072)     [16M,28M)
  bf16_t* Aout = ws + 28 * M1;                // attention out (4096 x 1024)    [28M,32M)

  prep_kernel<<<8192, 256, 0, stream>>>(hs, tk, tv, Wc, Wp, Ahs, Ktb, Vtb, WcT, WpT);
  qkv_gemm_kernel<<<768, 256, 0, stream>>>(Ahs, WcT, bc, Aqkv);
  attn_kernel<<<dim3(64, 8), 512, 0, stream>>>(Aqkv, Ktb, Vtb, Aout);
  gemm_out_kernel<<<dim3(8, 64), 256, 0, stream>>>(Aout, WpT, bp, out);
}

// Round 9
// 168.488 us; speedup vs baseline: 1.1589x; 1.1589x over previous
//
#include <hip/hip_runtime.h>

typedef __bf16 bf16_t;
typedef __bf16 bf16x8 __attribute__((ext_vector_type(8)));
typedef __bf16 bf16x4 __attribute__((ext_vector_type(4)));
typedef _Float16 f16x4 __attribute__((ext_vector_type(4)));
typedef _Float16 f16x8 __attribute__((ext_vector_type(8)));
typedef float f32x4 __attribute__((ext_vector_type(4)));

// async global->LDS, 16B per lane. LDS dest must be wave-uniform base + lane*16.
__device__ __forceinline__ void gl_lds16(const void* g, void* l) {
  __builtin_amdgcn_global_load_lds(
      (const __attribute__((address_space(1))) unsigned int*)g,
      (__attribute__((address_space(3))) unsigned int*)l, 16, 0, 0);
}

// ---------------------------------------------------------------- fused prep kernel
// [0,1024): cast hs->bf16 ; [1024,2048): cast tk->bf16  (16 elems/thread, 2x16B stores)
// [2048,3584): transpose Wc ; [3584,4096): transpose Wp ; [4096,6144): tv^T -> fp16 (key-permuted)
// Transposes: 64x32 fp32 tile in LDS, 16B vector stores.
__global__ __launch_bounds__(256) void prep_kernel(
    const float* __restrict__ hs, const float* __restrict__ tk, const float* __restrict__ tv,
    const float* __restrict__ Wc, const float* __restrict__ Wp,
    bf16_t* __restrict__ Ahs, bf16_t* __restrict__ Ktb, _Float16* __restrict__ Vtb,
    bf16_t* __restrict__ WcT, bf16_t* __restrict__ WpT) {
  const int blk = blockIdx.x;
  const int tid = threadIdx.x;
  if (blk < 2048) {
    const float4* src = (blk < 1024) ? (const float4*)hs : (const float4*)tk;
    bf16x8* dst = (blk < 1024) ? (bf16x8*)Ahs : (bf16x8*)Ktb;
    int i = (blk & 1023) * 256 + tid;  // units of 16 floats
    float4 v0 = src[4 * i], v1 = src[4 * i + 1], v2 = src[4 * i + 2], v3 = src[4 * i + 3];
    bf16x8 o0, o1;
    o0[0] = (bf16_t)v0.x; o0[1] = (bf16_t)v0.y; o0[2] = (bf16_t)v0.z; o0[3] = (bf16_t)v0.w;
    o0[4] = (bf16_t)v1.x; o0[5] = (bf16_t)v1.y; o0[6] = (bf16_t)v1.z; o0[7] = (bf16_t)v1.w;
    o1[0] = (bf16_t)v2.x; o1[1] = (bf16_t)v2.y; o1[2] = (bf16_t)v2.z; o1[3] = (bf16_t)v2.w;
    o1[4] = (bf16_t)v3.x; o1[5] = (bf16_t)v3.y; o1[6] = (bf16_t)v3.z; o1[7] = (bf16_t)v3.w;
    dst[2 * i] = o0; dst[2 * i + 1] = o1;
  } else {
    __shared__ float tile[32][65];  // [col][row], pad 65 -> 2-way max on write/read
    const float* in; bf16_t* out; int C, r0, c0; size_t base = 0; bool isV = false;
    if (blk < 3584) {
      int t = blk - 2048; in = Wc; out = WcT; C = 3072;
      r0 = (t / 96) * 64; c0 = (t % 96) * 32;
    } else if (blk < 4096) {
      int t = blk - 3584; in = Wp; out = WpT; C = 1024;
      r0 = (t >> 5) * 64; c0 = (t & 31) * 32;
    } else {
      int t = blk - 4096; int z = t >> 5, rest = t & 31;
      in = tv; out = nullptr; isV = true; C = 64; base = (size_t)z * 65536;
      r0 = (rest >> 1) * 64; c0 = (rest & 1) * 32;
    }
    // read 64 rows x 32 cols, write transposed into LDS
    {
      int rr = tid >> 2, cq = (tid & 3) << 3;
      const float* sp = in + base + (size_t)(r0 + rr) * C + c0 + cq;
      float4 v0 = *(const float4*)sp, v1 = *(const float4*)(sp + 4);
      tile[cq + 0][rr] = v0.x; tile[cq + 1][rr] = v0.y;
      tile[cq + 2][rr] = v0.z; tile[cq + 3][rr] = v0.w;
      tile[cq + 4][rr] = v1.x; tile[cq + 5][rr] = v1.y;
      tile[cq + 6][rr] = v1.z; tile[cq + 7][rr] = v1.w;
    }
    __syncthreads();
    int y = tid >> 3, l = tid & 7;
    if (isV) {
      // gather with key permutation m=b5,b3,b2,b4,b1,b0 (pairs PV chunk quads into 16B)
      f16x8 o;
#pragma unroll
      for (int j = 0; j < 8; j++) {
        int k = ((l & 4) << 3) | ((j & 4) << 2) | ((l & 2) << 2) | ((l & 1) << 2) | (j & 3);
        o[j] = (_Float16)tile[y][k];
      }
      *(f16x8*)(Vtb + base + (size_t)(c0 + y) * 1024 + r0 + (l << 3)) = o;
    } else {
      const float* rowp = &tile[y][l << 3];
      bf16x8 o;
#pragma unroll
      for (int j = 0; j < 8; j++) o[j] = (bf16_t)rowp[j];
      *(bf16x8*)(out + (size_t)(c0 + y) * 1024 + r0 + (l << 3)) = o;
    }
  }
}

// ---------------------------------------------------------------- fused qkv-GEMM + attention
// Two-strip blocks (R3-proven best: fused 44.9us): waves 0-3 own queries [64q,+64),
// waves 4-7 own [64(15-q),+64). 2-barrier phase-1 (at its structural ~860TF ceiling),
// flash phase-2 with T5 setprio.
#define ATTN_M 12.0f
__global__ __launch_bounds__(512, 4) void fused_attn_kernel(
    const bf16_t* __restrict__ Ahs, const bf16_t* __restrict__ WcT,
    const float* __restrict__ bc,
    const bf16_t* __restrict__ Ktxt, const _Float16* __restrict__ VtxtT,
    bf16_t* __restrict__ Aout) {
  const int bh = blockIdx.x;  // 0..63 ; id%8 = bh&7 -> h-locality per XCD
  const int y = blockIdx.y;   // 0..7
  const int q = (y < 4) ? y : 11 - y;  // co-resident pair (y,y+4) -> (q, 7-q)
  const int qlo = q, qhi = 15 - q;     // this block's two query strips (64 rows each)
  const int b = bh >> 4, h = bh & 15;
  const int tid = threadIdx.x, wave = tid >> 6, lane = tid & 63;
  const int c = lane & 15, qd = lane >> 4;
  const int i_base = (wave < 4) ? qlo * 64 + wave * 16 : qhi * 64 + (wave & 3) * 16;
  const int kt_max = qhi;  // inclusive; high strip needs tiles 0..15-q

  const bf16_t* Ktb = Ktxt + (size_t)bh * 65536;
  const _Float16* Vtb = VtxtT + (size_t)bh * 65536;

  __shared__ __align__(16) char pool[49152];
  bf16_t* Asm = (bf16_t*)pool;                // [0,16K)  phase 1
  bf16_t* Bsm = (bf16_t*)(pool + 16384);      // [16K,40K) phase 1
  bf16_t* Qsm = (bf16_t*)pool;                // [0,16K)  phase 2 (wave-private)
  bf16_t* KsmB = (bf16_t*)(pool + 16384);     // [16K,32K) Ksm[2][4096]
  _Float16* VsmB = (_Float16*)(pool + 32768); // [32K,48K) Vsm[2][4096]

  // ---------------- phase 1: 128x192 GEMM (q | k | v cols of head h), K=1024
  f32x4 acc[12];
#pragma unroll
  for (int j = 0; j < 12; j++) acc[j] = (f32x4){0.f, 0.f, 0.f, 0.f};

  for (int kt = 0; kt < 16; kt++) {
#pragma unroll
    for (int p = 0; p < 2; p++) {
      int chunk = p * 512 + tid;
      int row = chunk >> 3, sb = chunk & 7, kb = sb ^ (row & 7);
      int grow = b * 1024 + ((row < 64) ? qlo * 64 + row : qhi * 64 + (row - 64));
      gl_lds16(Ahs + (size_t)grow * 1024 + kt * 64 + kb * 8, Asm + chunk * 8);
    }
#pragma unroll
    for (int p = 0; p < 3; p++) {
      int chunk = p * 512 + tid;
      int brow = chunk >> 3, sb = chunk & 7, kb = sb ^ (brow & 7);
      int wrow = (brow >> 6) * 1024 + h * 64 + (brow & 63);
      gl_lds16(WcT + (size_t)wrow * 1024 + kt * 64 + kb * 8, Bsm + chunk * 8);
    }
    __syncthreads();
#pragma unroll
    for (int kk = 0; kk < 2; kk++) {
      int arow = wave * 16 + c;
      bf16x8 af = *(const bf16x8*)(&Asm[arow * 64 + (((4 * kk + qd) ^ (arow & 7)) << 3)]);
#pragma unroll
      for (int j = 0; j < 12; j++) {
        int brow = 16 * j + c;
        bf16x8 bf = *(const bf16x8*)(&Bsm[brow * 64 + (((4 * kk + qd) ^ (brow & 7)) << 3)]);
        acc[j] = __builtin_amdgcn_mfma_f32_16x16x32_bf16(af, bf, acc[j], 0, 0, 0);
      }
    }
    __syncthreads();
  }

  // stage K/V text tile 0 early (async, into the reused region)
  {
    int row = tid >> 3, sb = tid & 7, kb = sb ^ (row & 7);
    gl_lds16(Ktb + (size_t)row * 64 + kb * 8, KsmB + tid * 8);
    gl_lds16(Vtb + (size_t)row * 1024 + kb * 8, VsmB + tid * 8);
  }

  // bias
#pragma unroll
  for (int j = 0; j < 12; j++) {
    float bv = bc[(j >> 2) * 1024 + h * 64 + 16 * (j & 3) + c];
#pragma unroll
    for (int r = 0; r < 4; r++) acc[j][r] += bv;
  }

  // self logits: q.k per query
  float wself[4];
#pragma unroll
  for (int r = 0; r < 4; r++) {
    float part = acc[0][r] * acc[4][r] + acc[1][r] * acc[5][r] +
                 acc[2][r] * acc[6][r] + acc[3][r] * acc[7][r];
#pragma unroll
    for (int mk = 1; mk < 16; mk <<= 1) part += __shfl_xor(part, mk, 64);
    wself[r] = __expf(part * 0.125f - ATTN_M);
  }

  // O init: v C-frag is already in O layout
  f32x4 O[4];
#pragma unroll
  for (int u = 0; u < 4; u++)
#pragma unroll
    for (int r = 0; r < 4; r++) O[u][r] = wself[r] * acc[8 + u][r];

  // q: C-frag -> B-operand frag via wave-private LDS round-trip
  bf16_t* Qw = Qsm + wave * 1024;
#pragma unroll
  for (int j = 0; j < 4; j++) {
#pragma unroll
    for (int r = 0; r < 4; r++) {
      int ql = 4 * qd + r, d = 16 * j + c;
      int ch = (d >> 3) ^ (ql & 7);
      Qw[ql * 64 + (ch << 3) + (d & 7)] = (bf16_t)acc[j][r];
    }
  }
  bf16x8 aq[2];
#pragma unroll
  for (int kk = 0; kk < 2; kk++) {
    int ch = (4 * kk + qd) ^ (c & 7);
    aq[kk] = *(const bf16x8*)(&Qw[c * 64 + (ch << 3)]);
  }

  // ---------------- phase 2: flash attention over textual K/V
  float l_loc = 0.f;
  for (int kt = 0; kt <= kt_max; kt++) {
    __syncthreads();
    if (kt < kt_max) {
      int nb = (kt + 1) & 1;
      int row = tid >> 3, sb = tid & 7, kb = sb ^ (row & 7);
      gl_lds16(Ktb + (size_t)((kt + 1) * 64 + row) * 64 + kb * 8, KsmB + nb * 4096 + tid * 8);
      gl_lds16(Vtb + (size_t)row * 1024 + (kt + 1) * 64 + kb * 8, VsmB + nb * 4096 + tid * 8);
    }
    if (64 * kt >= i_base + 16) continue;  // wave fully masked for this tile
    const bf16_t* Ks = KsmB + (kt & 1) * 4096;
    const _Float16* Vs = VsmB + (kt & 1) * 4096;

    // S^T[key][query]: A = K-tile, B = Q  ->  C-frag: key = 16t+4qd+r, query = c
    f32x4 sc[4];
#pragma unroll
    for (int t = 0; t < 4; t++) sc[t] = (f32x4){0.f, 0.f, 0.f, 0.f};
    __builtin_amdgcn_s_setprio(1);  // T5: favor MFMA wave vs co-resident load-issuing waves
#pragma unroll
    for (int kk = 0; kk < 2; kk++) {
#pragma unroll
      for (int t = 0; t < 4; t++) {
        int row = 16 * t + c;
        bf16x8 bk = *(const bf16x8*)(&Ks[row * 64 + (((4 * kk + qd) ^ (row & 7)) << 3)]);
        sc[t] = __builtin_amdgcn_mfma_f32_16x16x32_bf16(bk, aq[kk], sc[t], 0, 0, 0);
      }
    }
    __builtin_amdgcn_s_setprio(0);
    const bool edge = (64 * kt + 63 >= i_base);
    f16x4 pa[4];  // P^T frags == A-operand of 16x16x16 f16 (m=query=c, k=4qd+j)
    if (!edge) {
#pragma unroll
      for (int t = 0; t < 4; t++)
#pragma unroll
        for (int r = 0; r < 4; r++) {
          float p = __expf(sc[t][r] * 0.125f - ATTN_M);
          l_loc += p;
          pa[t][r] = (_Float16)p;
        }
    } else {
#pragma unroll
      for (int t = 0; t < 4; t++)
#pragma unroll
        for (int r = 0; r < 4; r++) {
          bool masked = (64 * kt + 16 * t + 4 * qd + r >= i_base + c);
          float p = masked ? 0.f : __expf(sc[t][r] * 0.125f - ATTN_M);
          l_loc += p;
          pa[t][r] = (_Float16)p;
        }
    }
    // PV: V stored key-permuted so chunk-pair (2tp,2tp+1) quads sit in one 16B block
    __builtin_amdgcn_s_setprio(1);
#pragma unroll
    for (int tp = 0; tp < 2; tp++) {
#pragma unroll
      for (int u = 0; u < 4; u++) {
        int row = 16 * u + c;
        f16x8 vv = *(const f16x8*)(&Vs[row * 64 + (((4 * tp + qd) ^ (row & 7)) << 3)]);
        f16x4 vlo = __builtin_shufflevector(vv, vv, 0, 1, 2, 3);
        f16x4 vhi = __builtin_shufflevector(vv, vv, 4, 5, 6, 7);
        O[u] = __builtin_amdgcn_mfma_f32_16x16x16f16(pa[2 * tp], vlo, O[u], 0, 0, 0);
        O[u] = __builtin_amdgcn_mfma_f32_16x16x16f16(pa[2 * tp + 1], vhi, O[u], 0, 0, 0);
      }
    }
    __builtin_amdgcn_s_setprio(0);
  }

  l_loc += __shfl_xor(l_loc, 16, 64);
  l_loc += __shfl_xor(l_loc, 32, 64);
#pragma unroll
  for (int r = 0; r < 4; r++) {
    float lq = __shfl(l_loc, 4 * qd + r, 16);
    float inv = 1.0f / (lq + wself[r]);
    int i = i_base + 4 * qd + r;
#pragma unroll
    for (int u = 0; u < 4; u++)
      Aout[((size_t)b * 1024 + i) * 1024 + h * 64 + 16 * u + c] = (bf16_t)(O[u][r] * inv);
  }
}

// ---------------------------------------------------------------- GEMM 2: out = Aout @ Wp + bp
// 64x128 tile -> 512 blocks (2/CU, 16 waves/CU) + explicit LDS double-buffer.
// T1 XCD-contiguous swizzle: each XCD owns 8 consecutive m-tiles x all n-tiles.
__global__ __launch_bounds__(256) void gemm_out_kernel(
    const bf16_t* __restrict__ A, const bf16_t* __restrict__ Bt, const float* __restrict__ bias,
    float* __restrict__ out) {
  __shared__ bf16_t Asm[2][4096];
  __shared__ bf16_t Bsm[2][8192];
  const int bid = blockIdx.x;                   // 512 = 64 m-tiles x 8 n-tiles
  const int swz = (bid & 7) * 64 + (bid >> 3);  // 8 XCDs x 64 contiguous tiles
  const int m0 = (swz >> 3) * 64, n0 = (swz & 7) * 128;
  const int tid = threadIdx.x;
  const int wave = tid >> 6, lane = tid & 63;
  const int c = lane & 15, qd = lane >> 4;
  const int wn = wave * 32;

  f32x4 acc[4][2];
#pragma unroll
  for (int i = 0; i < 4; i++)
#pragma unroll
    for (int j = 0; j < 2; j++) acc[i][j] = (f32x4){0.f, 0.f, 0.f, 0.f};

#pragma unroll
  for (int p = 0; p < 2; p++) {
    int chunk = p * 256 + tid;
    int row = chunk >> 3, sb = chunk & 7, kb = sb ^ (row & 7);
    gl_lds16(A + (size_t)(m0 + row) * 1024 + kb * 8, &Asm[0][chunk * 8]);
  }
#pragma unroll
  for (int p = 0; p < 4; p++) {
    int chunk = p * 256 + tid;
    int row = chunk >> 3, sb = chunk & 7, kb = sb ^ (row & 7);
    gl_lds16(Bt + (size_t)(n0 + row) * 1024 + kb * 8, &Bsm[0][chunk * 8]);
  }
  for (int it = 0; it < 16; it++) {
    __syncthreads();
    if (it < 15) {
      int nbuf = (it + 1) & 1, kt = (it + 1) * 64;
#pragma unroll
      for (int p = 0; p < 2; p++) {
        int chunk = p * 256 + tid;
        int row = chunk >> 3, sb = chunk & 7, kb = sb ^ (row & 7);
        gl_lds16(A + (size_t)(m0 + row) * 1024 + kt + kb * 8, &Asm[nbuf][chunk * 8]);
      }
#pragma unroll
      for (int p = 0; p < 4; p++) {
        int chunk = p * 256 + tid;
        int row = chunk >> 3, sb = chunk & 7, kb = sb ^ (row & 7);
        gl_lds16(Bt + (size_t)(n0 + row) * 1024 + kt + kb * 8, &Bsm[nbuf][chunk * 8]);
      }
    }
    const int bs = it & 1;
#pragma unroll
    for (int kk = 0; kk < 2; kk++) {
      bf16x8 af[4], bfr[2];
#pragma unroll
      for (int i = 0; i < 4; i++) {
        int row = 16 * i + c;
        af[i] = *(const bf16x8*)(&Asm[bs][row * 64 + (((4 * kk + qd) ^ (row & 7)) << 3)]);
      }
#pragma unroll
      for (int j = 0; j < 2; j++) {
        int row = wn + 16 * j + c;
        bfr[j] = *(const bf16x8*)(&Bsm[bs][row * 64 + (((4 * kk + qd) ^ (row & 7)) << 3)]);
      }
#pragma unroll
      for (int i = 0; i < 4; i++)
#pragma unroll
        for (int j = 0; j < 2; j++)
          acc[i][j] = __builtin_amdgcn_mfma_f32_16x16x32_bf16(af[i], bfr[j], acc[i][j], 0, 0, 0);
    }
  }
#pragma unroll
  for (int j = 0; j < 2; j++) {
    int n = n0 + wn + 16 * j + c;
    float bv = bias[n];
#pragma unroll
    for (int i = 0; i < 4; i++) {
#pragma unroll
      for (int r = 0; r < 4; r++) {
        int m = m0 + 16 * i + 4 * qd + r;
        out[(size_t)m * 1024 + n] = acc[i][j][r] + bv;
      }
    }
  }
}

// ----------------------------------------------------------------
extern "C" void kernel_launch(void* const* d_in, const int* in_sizes, int n_in,
                              void* d_out, int out_size, void* d_ws, size_t ws_size,
                              hipStream_t stream) {
  const float* hs = (const float*)d_in[0];
  const float* tk = (const float*)d_in[1];
  const float* tv = (const float*)d_in[2];
  const float* Wc = (const float*)d_in[3];
  const float* bc = (const float*)d_in[4];
  const float* Wp = (const float*)d_in[5];
  const float* bp = (const float*)d_in[6];
  float* out = (float*)d_out;

  bf16_t* ws = (bf16_t*)d_ws;
  const size_t M1 = 1u << 20;
  bf16_t* Ahs  = ws;                          // hs bf16 (4096 x 1024)
  bf16_t* WcT  = ws + 4 * M1;                 // Wc^T (3072 x 1024)
  bf16_t* WpT  = ws + 7 * M1;                 // Wp^T (1024 x 1024)
  bf16_t* Ktb  = ws + 8 * M1;                 // textual_key bf16 (B,H,S,HD)
  _Float16* Vtb = (_Float16*)(ws + 12 * M1);  // textual_value^T fp16, key-permuted
  bf16_t* Aout = ws + 28 * M1;                // attention out, (B*S, D) bf16

  prep_kernel<<<6144, 256, 0, stream>>>(hs, tk, tv, Wc, Wp, Ahs, Ktb, Vtb, WcT, WpT);
  fused_attn_kernel<<<dim3(64, 8), 512, 0, stream>>>(Ahs, WcT, bc, Ktb, Vtb, Aout);
  gemm_out_kernel<<<512, 256, 0, stream>>>(Aout, WpT, bp, out);
}

// Round 10
// 168.158 us; speedup vs baseline: 1.1611x; 1.0020x over previous
//
#include <hip/hip_runtime.h>

typedef __bf16 bf16_t;
typedef __bf16 bf16x8 __attribute__((ext_vector_type(8)));
typedef __bf16 bf16x4 __attribute__((ext_vector_type(4)));
typedef _Float16 f16x4 __attribute__((ext_vector_type(4)));
typedef _Float16 f16x8 __attribute__((ext_vector_type(8)));
typedef float f32x4 __attribute__((ext_vector_type(4)));

// async global->LDS, 16B per lane. LDS dest must be wave-uniform base + lane*16.
__device__ __forceinline__ void gl_lds16(const void* g, void* l) {
  __builtin_amdgcn_global_load_lds(
      (const __attribute__((address_space(1))) unsigned int*)g,
      (__attribute__((address_space(3))) unsigned int*)l, 16, 0, 0);
}

// ---------------------------------------------------------------- fused prep kernel
// [0,1024): cast hs->bf16 ; [1024,2048): cast tk->bf16  (16 elems/thread, 2x16B stores)
// [2048,2816): transpose Wc ; [2816,3072): transpose Wp ; [3072,4096): tv^T -> fp16 (key-perm)
// Transposes: 64x64 fp32 tile in LDS (16.25KB), 4xfloat4 in / 2x16B out per thread.
__global__ __launch_bounds__(256) void prep_kernel(
    const float* __restrict__ hs, const float* __restrict__ tk, const float* __restrict__ tv,
    const float* __restrict__ Wc, const float* __restrict__ Wp,
    bf16_t* __restrict__ Ahs, bf16_t* __restrict__ Ktb, _Float16* __restrict__ Vtb,
    bf16_t* __restrict__ WcT, bf16_t* __restrict__ WpT) {
  const int blk = blockIdx.x;
  const int tid = threadIdx.x;
  if (blk < 2048) {
    const float4* src = (blk < 1024) ? (const float4*)hs : (const float4*)tk;
    bf16x8* dst = (blk < 1024) ? (bf16x8*)Ahs : (bf16x8*)Ktb;
    int i = (blk & 1023) * 256 + tid;  // units of 16 floats
    float4 v0 = src[4 * i], v1 = src[4 * i + 1], v2 = src[4 * i + 2], v3 = src[4 * i + 3];
    bf16x8 o0, o1;
    o0[0] = (bf16_t)v0.x; o0[1] = (bf16_t)v0.y; o0[2] = (bf16_t)v0.z; o0[3] = (bf16_t)v0.w;
    o0[4] = (bf16_t)v1.x; o0[5] = (bf16_t)v1.y; o0[6] = (bf16_t)v1.z; o0[7] = (bf16_t)v1.w;
    o1[0] = (bf16_t)v2.x; o1[1] = (bf16_t)v2.y; o1[2] = (bf16_t)v2.z; o1[3] = (bf16_t)v2.w;
    o1[4] = (bf16_t)v3.x; o1[5] = (bf16_t)v3.y; o1[6] = (bf16_t)v3.z; o1[7] = (bf16_t)v3.w;
    dst[2 * i] = o0; dst[2 * i + 1] = o1;
  } else {
    __shared__ float tile[64][65];  // [col][row]
    const float* in; bf16_t* out; int C, r0, c0; size_t base = 0; bool isV = false;
    if (blk < 2816) {
      int t = blk - 2048; in = Wc; out = WcT; C = 3072;    // 16 x 48 tiles
      r0 = (t / 48) * 64; c0 = (t % 48) * 64;
    } else if (blk < 3072) {
      int t = blk - 2816; in = Wp; out = WpT; C = 1024;    // 16 x 16 tiles
      r0 = (t >> 4) * 64; c0 = (t & 15) * 64;
    } else {
      int t = blk - 3072; int z = t >> 4, rest = t & 15;   // 64 z x 16 row-tiles
      in = tv; out = nullptr; isV = true; C = 64; base = (size_t)z * 65536;
      r0 = rest * 64; c0 = 0;
    }
    // read 64 rows x 64 cols, write transposed into LDS
    {
      int rr = tid >> 2, cq = (tid & 3) << 4;
      const float* sp = in + base + (size_t)(r0 + rr) * C + c0 + cq;
      float4 v0 = *(const float4*)sp, v1 = *(const float4*)(sp + 4);
      float4 v2 = *(const float4*)(sp + 8), v3 = *(const float4*)(sp + 12);
      tile[cq + 0][rr] = v0.x;  tile[cq + 1][rr] = v0.y;
      tile[cq + 2][rr] = v0.z;  tile[cq + 3][rr] = v0.w;
      tile[cq + 4][rr] = v1.x;  tile[cq + 5][rr] = v1.y;
      tile[cq + 6][rr] = v1.z;  tile[cq + 7][rr] = v1.w;
      tile[cq + 8][rr] = v2.x;  tile[cq + 9][rr] = v2.y;
      tile[cq + 10][rr] = v2.z; tile[cq + 11][rr] = v2.w;
      tile[cq + 12][rr] = v3.x; tile[cq + 13][rr] = v3.y;
      tile[cq + 14][rr] = v3.z; tile[cq + 15][rr] = v3.w;
    }
    __syncthreads();
    int yy = tid >> 3, l = tid & 7;
    if (isV) {
      // gather with key permutation over the 64-row (key) group
#pragma unroll
      for (int h2 = 0; h2 < 2; h2++) {
        int y = yy + 32 * h2;
        f16x8 o;
#pragma unroll
        for (int j = 0; j < 8; j++) {
          int k = ((l & 4) << 3) | ((j & 4) << 2) | ((l & 2) << 2) | ((l & 1) << 2) | (j & 3);
          o[j] = (_Float16)tile[y][k];
        }
        *(f16x8*)(Vtb + base + (size_t)(c0 + y) * 1024 + r0 + (l << 3)) = o;
      }
    } else {
#pragma unroll
      for (int h2 = 0; h2 < 2; h2++) {
        int y = yy + 32 * h2;
        const float* rowp = &tile[y][l << 3];
        bf16x8 o;
#pragma unroll
        for (int j = 0; j < 8; j++) o[j] = (bf16_t)rowp[j];
        *(bf16x8*)(out + (size_t)(c0 + y) * 1024 + r0 + (l << 3)) = o;
      }
    }
  }
}

// ---------------------------------------------------------------- fused qkv-GEMM + attention
// Two-strip blocks (R3-proven best: fused 44.9us): waves 0-3 own queries [64q,+64),
// waves 4-7 own [64(15-q),+64). 2-barrier phase-1 (at its structural ~860TF ceiling),
// flash phase-2 with T5 setprio.
#define ATTN_M 12.0f
__global__ __launch_bounds__(512, 4) void fused_attn_kernel(
    const bf16_t* __restrict__ Ahs, const bf16_t* __restrict__ WcT,
    const float* __restrict__ bc,
    const bf16_t* __restrict__ Ktxt, const _Float16* __restrict__ VtxtT,
    bf16_t* __restrict__ Aout) {
  const int bh = blockIdx.x;  // 0..63 ; id%8 = bh&7 -> h-locality per XCD
  const int y = blockIdx.y;   // 0..7
  const int q = (y < 4) ? y : 11 - y;  // co-resident pair (y,y+4) -> (q, 7-q)
  const int qlo = q, qhi = 15 - q;     // this block's two query strips (64 rows each)
  const int b = bh >> 4, h = bh & 15;
  const int tid = threadIdx.x, wave = tid >> 6, lane = tid & 63;
  const int c = lane & 15, qd = lane >> 4;
  const int i_base = (wave < 4) ? qlo * 64 + wave * 16 : qhi * 64 + (wave & 3) * 16;
  const int kt_max = qhi;  // inclusive; high strip needs tiles 0..15-q

  const bf16_t* Ktb = Ktxt + (size_t)bh * 65536;
  const _Float16* Vtb = VtxtT + (size_t)bh * 65536;

  __shared__ __align__(16) char pool[49152];
  bf16_t* Asm = (bf16_t*)pool;                // [0,16K)  phase 1
  bf16_t* Bsm = (bf16_t*)(pool + 16384);      // [16K,40K) phase 1
  bf16_t* Qsm = (bf16_t*)pool;                // [0,16K)  phase 2 (wave-private)
  bf16_t* KsmB = (bf16_t*)(pool + 16384);     // [16K,32K) Ksm[2][4096]
  _Float16* VsmB = (_Float16*)(pool + 32768); // [32K,48K) Vsm[2][4096]

  // ---------------- phase 1: 128x192 GEMM (q | k | v cols of head h), K=1024
  f32x4 acc[12];
#pragma unroll
  for (int j = 0; j < 12; j++) acc[j] = (f32x4){0.f, 0.f, 0.f, 0.f};

  for (int kt = 0; kt < 16; kt++) {
#pragma unroll
    for (int p = 0; p < 2; p++) {
      int chunk = p * 512 + tid;
      int row = chunk >> 3, sb = chunk & 7, kb = sb ^ (row & 7);
      int grow = b * 1024 + ((row < 64) ? qlo * 64 + row : qhi * 64 + (row - 64));
      gl_lds16(Ahs + (size_t)grow * 1024 + kt * 64 + kb * 8, Asm + chunk * 8);
    }
#pragma unroll
    for (int p = 0; p < 3; p++) {
      int chunk = p * 512 + tid;
      int brow = chunk >> 3, sb = chunk & 7, kb = sb ^ (brow & 7);
      int wrow = (brow >> 6) * 1024 + h * 64 + (brow & 63);
      gl_lds16(WcT + (size_t)wrow * 1024 + kt * 64 + kb * 8, Bsm + chunk * 8);
    }
    __syncthreads();
#pragma unroll
    for (int kk = 0; kk < 2; kk++) {
      int arow = wave * 16 + c;
      bf16x8 af = *(const bf16x8*)(&Asm[arow * 64 + (((4 * kk + qd) ^ (arow & 7)) << 3)]);
#pragma unroll
      for (int j = 0; j < 12; j++) {
        int brow = 16 * j + c;
        bf16x8 bf = *(const bf16x8*)(&Bsm[brow * 64 + (((4 * kk + qd) ^ (brow & 7)) << 3)]);
        acc[j] = __builtin_amdgcn_mfma_f32_16x16x32_bf16(af, bf, acc[j], 0, 0, 0);
      }
    }
    __syncthreads();
  }

  // stage K/V text tile 0 early (async, into the reused region)
  {
    int row = tid >> 3, sb = tid & 7, kb = sb ^ (row & 7);
    gl_lds16(Ktb + (size_t)row * 64 + kb * 8, KsmB + tid * 8);
    gl_lds16(Vtb + (size_t)row * 1024 + kb * 8, VsmB + tid * 8);
  }

  // bias
#pragma unroll
  for (int j = 0; j < 12; j++) {
    float bv = bc[(j >> 2) * 1024 + h * 64 + 16 * (j & 3) + c];
#pragma unroll
    for (int r = 0; r < 4; r++) acc[j][r] += bv;
  }

  // self logits: q.k per query
  float wself[4];
#pragma unroll
  for (int r = 0; r < 4; r++) {
    float part = acc[0][r] * acc[4][r] + acc[1][r] * acc[5][r] +
                 acc[2][r] * acc[6][r] + acc[3][r] * acc[7][r];
#pragma unroll
    for (int mk = 1; mk < 16; mk <<= 1) part += __shfl_xor(part, mk, 64);
    wself[r] = __expf(part * 0.125f - ATTN_M);
  }

  // O init: v C-frag is already in O layout
  f32x4 O[4];
#pragma unroll
  for (int u = 0; u < 4; u++)
#pragma unroll
    for (int r = 0; r < 4; r++) O[u][r] = wself[r] * acc[8 + u][r];

  // q: C-frag -> B-operand frag via wave-private LDS round-trip
  bf16_t* Qw = Qsm + wave * 1024;
#pragma unroll
  for (int j = 0; j < 4; j++) {
#pragma unroll
    for (int r = 0; r < 4; r++) {
      int ql = 4 * qd + r, d = 16 * j + c;
      int ch = (d >> 3) ^ (ql & 7);
      Qw[ql * 64 + (ch << 3) + (d & 7)] = (bf16_t)acc[j][r];
    }
  }
  bf16x8 aq[2];
#pragma unroll
  for (int kk = 0; kk < 2; kk++) {
    int ch = (4 * kk + qd) ^ (c & 7);
    aq[kk] = *(const bf16x8*)(&Qw[c * 64 + (ch << 3)]);
  }

  // ---------------- phase 2: flash attention over textual K/V
  float l_loc = 0.f;
  for (int kt = 0; kt <= kt_max; kt++) {
    __syncthreads();
    if (kt < kt_max) {
      int nb = (kt + 1) & 1;
      int row = tid >> 3, sb = tid & 7, kb = sb ^ (row & 7);
      gl_lds16(Ktb + (size_t)((kt + 1) * 64 + row) * 64 + kb * 8, KsmB + nb * 4096 + tid * 8);
      gl_lds16(Vtb + (size_t)row * 1024 + (kt + 1) * 64 + kb * 8, VsmB + nb * 4096 + tid * 8);
    }
    if (64 * kt >= i_base + 16) continue;  // wave fully masked for this tile
    const bf16_t* Ks = KsmB + (kt & 1) * 4096;
    const _Float16* Vs = VsmB + (kt & 1) * 4096;

    // S^T[key][query]: A = K-tile, B = Q  ->  C-frag: key = 16t+4qd+r, query = c
    f32x4 sc[4];
#pragma unroll
    for (int t = 0; t < 4; t++) sc[t] = (f32x4){0.f, 0.f, 0.f, 0.f};
    __builtin_amdgcn_s_setprio(1);  // T5: favor MFMA wave vs co-resident load-issuing waves
#pragma unroll
    for (int kk = 0; kk < 2; kk++) {
#pragma unroll
      for (int t = 0; t < 4; t++) {
        int row = 16 * t + c;
        bf16x8 bk = *(const bf16x8*)(&Ks[row * 64 + (((4 * kk + qd) ^ (row & 7)) << 3)]);
        sc[t] = __builtin_amdgcn_mfma_f32_16x16x32_bf16(bk, aq[kk], sc[t], 0, 0, 0);
      }
    }
    __builtin_amdgcn_s_setprio(0);
    const bool edge = (64 * kt + 63 >= i_base);
    f16x4 pa[4];  // P^T frags == A-operand of 16x16x16 f16 (m=query=c, k=4qd+j)
    if (!edge) {
#pragma unroll
      for (int t = 0; t < 4; t++)
#pragma unroll
        for (int r = 0; r < 4; r++) {
          float p = __expf(sc[t][r] * 0.125f - ATTN_M);
          l_loc += p;
          pa[t][r] = (_Float16)p;
        }
    } else {
#pragma unroll
      for (int t = 0; t < 4; t++)
#pragma unroll
        for (int r = 0; r < 4; r++) {
          bool masked = (64 * kt + 16 * t + 4 * qd + r >= i_base + c);
          float p = masked ? 0.f : __expf(sc[t][r] * 0.125f - ATTN_M);
          l_loc += p;
          pa[t][r] = (_Float16)p;
        }
    }
    // PV: V stored key-permuted so chunk-pair (2tp,2tp+1) quads sit in one 16B block
    __builtin_amdgcn_s_setprio(1);
#pragma unroll
    for (int tp = 0; tp < 2; tp++) {
#pragma unroll
      for (int u = 0; u < 4; u++) {
        int row = 16 * u + c;
        f16x8 vv = *(const f16x8*)(&Vs[row * 64 + (((4 * tp + qd) ^ (row & 7)) << 3)]);
        f16x4 vlo = __builtin_shufflevector(vv, vv, 0, 1, 2, 3);
        f16x4 vhi = __builtin_shufflevector(vv, vv, 4, 5, 6, 7);
        O[u] = __builtin_amdgcn_mfma_f32_16x16x16f16(pa[2 * tp], vlo, O[u], 0, 0, 0);
        O[u] = __builtin_amdgcn_mfma_f32_16x16x16f16(pa[2 * tp + 1], vhi, O[u], 0, 0, 0);
      }
    }
    __builtin_amdgcn_s_setprio(0);
  }

  l_loc += __shfl_xor(l_loc, 16, 64);
  l_loc += __shfl_xor(l_loc, 32, 64);
#pragma unroll
  for (int r = 0; r < 4; r++) {
    float lq = __shfl(l_loc, 4 * qd + r, 16);
    float inv = 1.0f / (lq + wself[r]);
    int i = i_base + 4 * qd + r;
#pragma unroll
    for (int u = 0; u < 4; u++)
      Aout[((size_t)b * 1024 + i) * 1024 + h * 64 + 16 * u + c] = (bf16_t)(O[u][r] * inv);
  }
}

// ---------------------------------------------------------------- GEMM 2: out = Aout @ Wp + bp
// 128x128 tile, 512 thr / 8 waves (2x4, 64x32 each) -> 256 blocks (1/CU), LDS dbuf 64KB,
// stage-under-compute. FLOP/staged-byte 65.5 (was 43.7); L2 traffic 128MB (was 192MB).
// T1 XCD-contiguous swizzle: each XCD owns 4 m-rows x all 8 n-tiles (3MB working set < 4MB L2).
__global__ __launch_bounds__(512) void gemm_out_kernel(
    const bf16_t* __restrict__ A, const bf16_t* __restrict__ Bt, const float* __restrict__ bias,
    float* __restrict__ out) {
  __shared__ bf16_t Asm[2][8192];
  __shared__ bf16_t Bsm[2][8192];
  const int bid = blockIdx.x;                   // 256 = 32 m-tiles x 8 n-tiles
  const int swz = (bid & 7) * 32 + (bid >> 3);  // 8 XCDs x 32 contiguous tiles
  const int m0 = (swz >> 3) * 128, n0 = (swz & 7) * 128;
  const int tid = threadIdx.x;
  const int wave = tid >> 6, lane = tid & 63;
  const int c = lane & 15, qd = lane >> 4;
  const int wr = wave >> 2, wc = wave & 3;  // wave tile: rows [wr*64,+64) x cols [wc*32,+32)

  f32x4 acc[4][2];
#pragma unroll
  for (int i = 0; i < 4; i++)
#pragma unroll
    for (int j = 0; j < 2; j++) acc[i][j] = (f32x4){0.f, 0.f, 0.f, 0.f};

#pragma unroll
  for (int p = 0; p < 2; p++) {
    int chunk = p * 512 + tid;
    int row = chunk >> 3, sb = chunk & 7, kb = sb ^ (row & 7);
    gl_lds16(A + (size_t)(m0 + row) * 1024 + kb * 8, &Asm[0][chunk * 8]);
    gl_lds16(Bt + (size_t)(n0 + row) * 1024 + kb * 8, &Bsm[0][chunk * 8]);
  }
  for (int it = 0; it < 16; it++) {
    __syncthreads();
    if (it < 15) {
      int nbuf = (it + 1) & 1, kt = (it + 1) * 64;
#pragma unroll
      for (int p = 0; p < 2; p++) {
        int chunk = p * 512 + tid;
        int row = chunk >> 3, sb = chunk & 7, kb = sb ^ (row & 7);
        gl_lds16(A + (size_t)(m0 + row) * 1024 + kt + kb * 8, &Asm[nbuf][chunk * 8]);
        gl_lds16(Bt + (size_t)(n0 + row) * 1024 + kt + kb * 8, &Bsm[nbuf][chunk * 8]);
      }
    }
    const int bs = it & 1;
#pragma unroll
    for (int kk = 0; kk < 2; kk++) {
      bf16x8 af[4], bfr[2];
#pragma unroll
      for (int i = 0; i < 4; i++) {
        int row = wr * 64 + 16 * i + c;
        af[i] = *(const bf16x8*)(&Asm[bs][row * 64 + (((4 * kk + qd) ^ (row & 7)) << 3)]);
      }
#pragma unroll
      for (int j = 0; j < 2; j++) {
        int row = wc * 32 + 16 * j + c;
        bfr[j] = *(const bf16x8*)(&Bsm[bs][row * 64 + (((4 * kk + qd) ^ (row & 7)) << 3)]);
      }
#pragma unroll
      for (int i = 0; i < 4; i++)
#pragma unroll
        for (int j = 0; j < 2; j++)
          acc[i][j] = __builtin_amdgcn_mfma_f32_16x16x32_bf16(af[i], bfr[j], acc[i][j], 0, 0, 0);
    }
  }
#pragma unroll
  for (int j = 0; j < 2; j++) {
    int n = n0 + wc * 32 + 16 * j + c;
    float bv = bias[n];
#pragma unroll
    for (int i = 0; i < 4; i++) {
#pragma unroll
      for (int r = 0; r < 4; r++) {
        int m = m0 + wr * 64 + 16 * i + 4 * qd + r;
        out[(size_t)m * 1024 + n] = acc[i][j][r] + bv;
      }
    }
  }
}

// ----------------------------------------------------------------
extern "C" void kernel_launch(void* const* d_in, const int* in_sizes, int n_in,
                              void* d_out, int out_size, void* d_ws, size_t ws_size,
                              hipStream_t stream) {
  const float* hs = (const float*)d_in[0];
  const float* tk = (const float*)d_in[1];
  const float* tv = (const float*)d_in[2];
  const float* Wc = (const float*)d_in[3];
  const float* bc = (const float*)d_in[4];
  const float* Wp = (const float*)d_in[5];
  const float* bp = (const float*)d_in[6];
  float* out = (float*)d_out;

  bf16_t* ws = (bf16_t*)d_ws;
  const size_t M1 = 1u << 20;
  bf16_t* Ahs  = ws;                          // hs bf16 (4096 x 1024)
  bf16_t* WcT  = ws + 4 * M1;                 // Wc^T (3072 x 1024)
  bf16_t* WpT  = ws + 7 * M1;                 // Wp^T (1024 x 1024)
  bf16_t* Ktb  = ws + 8 * M1;                 // textual_key bf16 (B,H,S,HD)
  _Float16* Vtb = (_Float16*)(ws + 12 * M1);  // textual_value^T fp16, key-permuted
  bf16_t* Aout = ws + 28 * M1;                // attention out, (B*S, D) bf16

  prep_kernel<<<4096, 256, 0, stream>>>(hs, tk, tv, Wc, Wp, Ahs, Ktb, Vtb, WcT, WpT);
  fused_attn_kernel<<<dim3(64, 8), 512, 0, stream>>>(Ahs, WcT, bc, Ktb, Vtb, Aout);
  gemm_out_kernel<<<256, 512, 0, stream>>>(Aout, WpT, bp, out);
}